// Round 22
// baseline (143.155 us; speedup 1.0000x reference)
//
#include <hip/hip_runtime.h>

typedef unsigned char u8;
typedef float f32x4 __attribute__((ext_vector_type(4)));
typedef _Float16 f16x8 __attribute__((ext_vector_type(8)));

#define DIM 128
#define TM  128
// Spill rules (r17/r20/r21): (a) never wrap the MFMA block in a runtime loop;
// (b) MFMA kernels ONLY at 4- or 8-wave blocks with __launch_bounds__(N,4) --
// 576-thread (9-wave) MFMA kernels get an 84-VGPR cap from the backend
// regardless of the min-waves arg and spill ~42MB to scratch.

__device__ __forceinline__ float fast_tanh(float x) {
    // tanh(x) = 1 - 2/(exp2(2x*log2e)+1); exact +-1 saturation via inf->0
    float e = __builtin_amdgcn_exp2f(x * 2.885390081777927f);
    return 1.0f - 2.0f * __builtin_amdgcn_rcpf(e + 1.0f);
}
__device__ __forceinline__ float fast_sigmoid(float x) {
    float e = __builtin_amdgcn_exp2f(x * -1.4426950408889634f);
    return __builtin_amdgcn_rcpf(1.0f + e);
}

// stage W2^T (fp16, XOR-swizzled 16B chunks) into LDS; any thread count
__device__ __forceinline__ void stage_w2(const float* __restrict__ W2,
                                         _Float16* sW2T, int tid, int nt) {
    for (int chunk = tid; chunk < 2048; chunk += nt) {
        int n = chunk & 127, ko = chunk >> 7;
        f16x8 v;
        #pragma unroll
        for (int qq = 0; qq < 8; ++qq)
            v[qq] = (_Float16)W2[(ko * 8 + qq) * DIM + n];   // coalesced over n
        int slot = ko ^ (n & 15);
        *(f16x8*)&sW2T[n * DIM + slot * 8] = v;
    }
}

// one wave: 32 points (2 A-frags) x 128 dims; b2 folded into acc init.
// rs[mf][rg] = sum_c tanh(h2)*W3, lane-reduced (valid on all lanes).
// C/D: point-row = mf*16 + lg*4 + rg.  NO barriers inside (per-wave safe).
__device__ __forceinline__ void mlp_wave(
    const float xs[2], const float ys[2], const _Float16* sW2T,
    const float* __restrict__ W1, const float* __restrict__ b1,
    const float* __restrict__ b2, const float* __restrict__ W3,
    int lg, int l15, float rs[2][4])
{
    f32x4 acc[2][8];
    #pragma unroll
    for (int nf = 0; nf < 8; ++nf) {
        float b2v = b2[nf * 16 + l15];
        acc[0][nf] = (f32x4)(b2v);
        acc[1][nf] = (f32x4)(b2v);
    }
    #pragma unroll
    for (int kf = 0; kf < 4; ++kf) {
        const int kbase = kf * 32 + lg * 8;
        f16x8 bh[8];
        #pragma unroll
        for (int nf = 0; nf < 8; ++nf) {
            int cc = nf * 16 + l15;
            int slot = (kf * 4 + lg) ^ l15;   // matches stage_w2 swizzle
            bh[nf] = *(const f16x8*)&sW2T[cc * DIM + slot * 8];
        }
        f32x4 wxa = *(const f32x4*)&W1[kbase];
        f32x4 wxb = *(const f32x4*)&W1[kbase + 4];
        f32x4 wya = *(const f32x4*)&W1[DIM + kbase];
        f32x4 wyb = *(const f32x4*)&W1[DIM + kbase + 4];
        f32x4 b1a = *(const f32x4*)&b1[kbase];
        f32x4 b1b = *(const f32x4*)&b1[kbase + 4];
        f16x8 ah[2];
        #pragma unroll
        for (int mf = 0; mf < 2; ++mf) {
            float x = xs[mf], y = ys[mf];
            #pragma unroll
            for (int qq = 0; qq < 4; ++qq)
                ah[mf][qq] = (_Float16)fast_tanh(fmaf(x, wxa[qq], fmaf(y, wya[qq], b1a[qq])));
            #pragma unroll
            for (int qq = 0; qq < 4; ++qq)
                ah[mf][4 + qq] = (_Float16)fast_tanh(fmaf(x, wxb[qq], fmaf(y, wyb[qq], b1b[qq])));
        }
        #pragma unroll
        for (int nf = 0; nf < 8; ++nf)
            #pragma unroll
            for (int mf = 0; mf < 2; ++mf)
                acc[mf][nf] = __builtin_amdgcn_mfma_f32_16x16x32_f16(ah[mf], bh[nf], acc[mf][nf], 0, 0, 0);
    }
    #pragma unroll
    for (int mf = 0; mf < 2; ++mf)
        #pragma unroll
        for (int rg = 0; rg < 4; ++rg) rs[mf][rg] = 0.0f;
    #pragma unroll
    for (int nf = 0; nf < 8; ++nf) {
        float w3v = W3[nf * 16 + l15];
        #pragma unroll
        for (int mf = 0; mf < 2; ++mf)
            #pragma unroll
            for (int rg = 0; rg < 4; ++rg)
                rs[mf][rg] += fast_tanh(acc[mf][nf][rg]) * w3v;
    }
    #pragma unroll
    for (int mf = 0; mf < 2; ++mf)
        #pragma unroll
        for (int rg = 0; rg < 4; ++rg) {
            float v = rs[mf][rg];
            v += __shfl_xor(v, 1);
            v += __shfl_xor(v, 2);
            v += __shfl_xor(v, 4);
            v += __shfl_xor(v, 8);
            rs[mf][rg] = v;
        }
}

// ---- dense MLP eval of an RxR grid (R-1 power of two); straight-line ----
__global__ __launch_bounds__(256, 4) void eval_grid(
    const float* __restrict__ W1, const float* __restrict__ b1,
    const float* __restrict__ W2, const float* __restrict__ b2,
    const float* __restrict__ W3, const float* __restrict__ b3,
    const float* __restrict__ bmin, const float* __restrict__ bmax,
    float* __restrict__ out, int R)
{
    __shared__ __align__(16) _Float16 sW2T[DIM * DIM];   // 32 KB
    const int N = R * R;
    const int tid = threadIdx.x;
    const int m0 = blockIdx.x * TM;
    stage_w2(W2, sW2T, tid, 256);

    const int w = tid >> 6, lane = tid & 63;
    const int l15 = lane & 15, lg = lane >> 4;

    const float inv = 1.0f / (float)(R - 1);   // power-of-two -> exact
    const float bx0 = bmin[0], by0 = bmin[1];
    const float sx = bmax[0] - bx0, sy = bmax[1] - by0;
    float xs[2], ys[2];
    #pragma unroll
    for (int mf = 0; mf < 2; ++mf) {
        int pi = m0 + w * 32 + mf * 16 + l15;
        int pg = (pi < N) ? pi : N - 1;
        int gi = pg / R, gj = pg - gi * R;
        xs[mf] = bx0 + (float)gj * inv * sx;
        ys[mf] = by0 + (float)gi * inv * sy;
    }
    __syncthreads();

    float rs[2][4];
    mlp_wave(xs, ys, sW2T, W1, b1, b2, W3, lg, l15, rs);
    if (l15 == 0) {
        float b3v = b3[0];
        #pragma unroll
        for (int mf = 0; mf < 2; ++mf)
            #pragma unroll
            for (int rg = 0; rg < 4; ++rg) {
                int po = m0 + w * 32 + mf * 16 + lg * 4 + rg;
                if (po < N) out[po] = fast_sigmoid(rs[mf][rg] + b3v);
            }
    }
}

// ---- one refinement level on a 24x24 window, one thread per cell ----
#define HWF 24
#define NTF 576
template<bool FIRST>
__device__ __forceinline__ void run_level(
    int c, int li, int lj, int oi0, int oj0, int R,
    const float* __restrict__ qbuf, int qpitch, int qs,
    const float* __restrict__ q257, int pOi, int pOj,
    const float* sOccP, const u8* sCalP,
    u8* sRaw, u8* sCfA, u8* sCfB,
    float& occR, bool& calR)
{
    const float BAL = 0.5f;
    const int fi = oi0 + li, fj = oj0 + lj;
    const bool inG = (fi >= 0 && fi < R && fj >= 0 && fj < R);
    float occ = 0.5f, qv = 0.5f;
    u8 rw = 0; bool cal = false;
    if (inG) qv = qbuf[(fi * qs) * qpitch + fj * qs];   // issued early, used late
    if (inG) {
        int ip = fi >> 1, jp = fj >> 1;
        int oi = fi & 1, oj = fj & 1;
        float tl = FIRST ? q257[(ip * 8) * 257 + jp * 8]
                         : sOccP[(ip - pOi) * HWF + (jp - pOj)];
        bool b;
        if (!oi && !oj) { occ = tl; b = false; }
        else if (oi && !oj) {
            float bl = FIRST ? q257[((ip + 1) * 8) * 257 + jp * 8]
                             : sOccP[(ip + 1 - pOi) * HWF + (jp - pOj)];
            occ = 0.5f * (tl + bl);
            b = (tl > BAL) != (bl > BAL);
        } else if (!oi && oj) {
            float tr = FIRST ? q257[(ip * 8) * 257 + (jp + 1) * 8]
                             : sOccP[(ip - pOi) * HWF + (jp + 1 - pOj)];
            occ = 0.5f * (tl + tr);
            b = (tl > BAL) != (tr > BAL);
        } else {
            float bl = FIRST ? q257[((ip + 1) * 8) * 257 + jp * 8]
                             : sOccP[(ip + 1 - pOi) * HWF + (jp - pOj)];
            float tr = FIRST ? q257[(ip * 8) * 257 + (jp + 1) * 8]
                             : sOccP[(ip - pOi) * HWF + (jp + 1 - pOj)];
            float br = FIRST ? q257[((ip + 1) * 8) * 257 + (jp + 1) * 8]
                             : sOccP[(ip + 1 - pOi) * HWF + (jp + 1 - pOj)];
            occ = 0.5f * (0.5f * (tl + bl) + 0.5f * (tr + br));  // exact _up2 order
            bool m0 = tl > BAL, m1 = bl > BAL, m2 = tr > BAL, m3 = br > BAL;
            b = (m0 | m1 | m2 | m3) && !(m0 & m1 & m2 & m3);
        }
        rw = b ? 1 : 0;
        if (((fi | fj) & 1) == 0)
            cal = FIRST ? true : (sCalP[(ip - pOi) * HWF + (jp - pOj)] != 0);
    }
    sRaw[c] = rw; sCfA[c] = 0; sCfB[c] = 0;

    if (__syncthreads_or(rw)) {
        u8 cf = 0;
        if (li >= 1 && li < HWF - 1 && lj >= 1 && lj < HWF - 1 && inG) {
            bool b = false;
            #pragma unroll
            for (int di = -1; di <= 1; ++di)
                #pragma unroll
                for (int dj = -1; dj <= 1; ++dj)
                    if (sRaw[(li + di) * HWF + (lj + dj)]) b = true;
            b = b && !cal;
            cf = (b && (occ - BAL) * (qv - BAL) < 0.0f) ? 1 : 0;
            if (b) { occ = qv; cal = true; }
            sCfA[c] = cf;
        }
        int haveCf = __syncthreads_or((int)cf);

        #pragma unroll
        for (int it = 0; it < 3; ++it) {
            if (!haveCf) break;
            const u8* cin = (it & 1) ? sCfB : sCfA;
            u8* cout      = (it & 1) ? sCfA : sCfB;
            int lo = 2 + it, hi = HWF - 2 - it;
            u8 nc = 0;
            if (li >= lo && li < hi && lj >= lo && lj < hi && inG) {
                bool any = false;
                #pragma unroll
                for (int di = -1; di <= 1; ++di)
                    #pragma unroll
                    for (int dj = -1; dj <= 1; ++dj)
                        if (cin[(li + di) * HWF + (lj + dj)]) any = true;
                bool cand = any && !cal;
                nc = (cand && (occ - BAL) * (qv - BAL) < 0.0f) ? 1 : 0;
                if (cand) { occ = qv; cal = true; }
                cout[c] = nc;
            }
            haveCf = __syncthreads_or((int)nc);
        }
    }
    occR = occ; calR = cal;
}

// ---- levels 1-3 fused, one block per 16x16 tile of the 257 grid (stencil only) ----
__global__ __launch_bounds__(NTF) void levels123_fused(
    const float* __restrict__ q257,
    float* __restrict__ occ257, u8* __restrict__ cal257)
{
    __shared__ float sOcc[NTF];
    __shared__ u8 sCal[NTF], sRaw[NTF], sCfA[NTF], sCfB[NTF];
    const int bi = blockIdx.x / 17, bj = blockIdx.x - bi * 17;
    const int c = threadIdx.x;
    const int li = c / HWF, lj = c - li * HWF;
    float occ; bool cal;

    run_level<true>(c, li, lj, 4 * bi - 7, 4 * bj - 7, 65,
                    q257, 257, 4, q257, 0, 0,
                    sOcc, sCal, sRaw, sCfA, sCfB, occ, cal);
    sOcc[c] = occ; sCal[c] = cal ? 1 : 0;
    __syncthreads();
    run_level<false>(c, li, lj, 8 * bi - 6, 8 * bj - 6, 129,
                     q257, 257, 2, q257, 4 * bi - 7, 4 * bj - 7,
                     sOcc, sCal, sRaw, sCfA, sCfB, occ, cal);
    sOcc[c] = occ; sCal[c] = cal ? 1 : 0;
    __syncthreads();
    run_level<false>(c, li, lj, 16 * bi - 4, 16 * bj - 4, 257,
                     q257, 257, 1, q257, 8 * bi - 6, 8 * bj - 6,
                     sOcc, sCal, sRaw, sCfA, sCfB, occ, cal);

    const int fi = 16 * bi - 4 + li, fj = 16 * bj - 4 + lj;
    if (li >= 4 && li < 20 && lj >= 4 && lj < 20 && fi < 257 && fj < 257) {
        occ257[fi * 257 + fj] = occ;
        cal257[fi * 257 + fj] = cal ? 1 : 0;
    }
}

// ---- per-cell upsample+raw helper (no MFMA state) ----
__device__ __forceinline__ void upsample_cell(
    int fi, int fj, bool inG,
    const float* __restrict__ occP, const u8* __restrict__ calcP,
    float& occ, u8& rw, bool& cal)
{
    const float BAL = 0.5f;
    occ = 0.5f; rw = 0; cal = false;
    if (!inG) return;
    int ip = fi >> 1, jp = fj >> 1;
    float tl = occP[ip * 257 + jp];
    int oi = fi & 1, oj = fj & 1;
    bool b;
    if (!oi && !oj) { occ = tl; b = false; }
    else if (oi && !oj) {
        float bl = occP[(ip + 1) * 257 + jp];
        occ = 0.5f * (tl + bl);
        b = (tl > BAL) != (bl > BAL);
    } else if (!oi && oj) {
        float tr = occP[ip * 257 + jp + 1];
        occ = 0.5f * (tl + tr);
        b = (tl > BAL) != (tr > BAL);
    } else {
        float bl = occP[(ip + 1) * 257 + jp];
        float tr = occP[ip * 257 + jp + 1];
        float br = occP[(ip + 1) * 257 + jp + 1];
        occ = 0.5f * (0.5f * (tl + bl) + 0.5f * (tr + br));  // exact _up2 order
        bool m0 = tl > BAL, m1 = bl > BAL, m2 = tr > BAL, m3 = br > BAL;
        b = (m0 | m1 | m2 | m3) && !(m0 & m1 & m2 & m3);
    }
    rw = b ? 1 : 0;
    if (((fi | fj) & 1) == 0) cal = calcP[ip * 257 + jp] != 0;
}

// ---- level 4 + in-tile fine eval, 512 threads (8 waves, proven no-spill) ----
// Thread tid owns cell tid; threads 0..63 also own cells 512..575 (rows 21-23,
// pure halo -- stencil context only, never written out). MLP = 2 full
// straight-line mlp_wave calls + 1 predicated to waves 0-1. Cell state parks
// in LDS across the MFMA phase (keeps MFMA liveness == r19's proven eval_fine).
__global__ __launch_bounds__(512, 4) void level4_fused(
    const float* __restrict__ W1, const float* __restrict__ b1,
    const float* __restrict__ W2, const float* __restrict__ b2,
    const float* __restrict__ W3, const float* __restrict__ b3,
    const float* __restrict__ bmin, const float* __restrict__ bmax,
    const float* __restrict__ occP, const u8* __restrict__ calcP,
    float* __restrict__ out)
{
    __shared__ __align__(16) _Float16 sW2T[DIM * DIM];   // 32 KB
    __shared__ float sQ[NTF], sOccS[NTF];
    __shared__ u8 sCalS[NTF], sRaw[NTF], sCfA[NTF], sCfB[NTF];
    const int bi = blockIdx.x / 33, bj = blockIdx.x - bi * 33;
    const int fi0 = bi * 16 - 4, fj0 = bj * 16 - 4;
    const int tid = threadIdx.x;
    const float BAL = 0.5f;

    // cell 0: tid; cell 1: tid+512 (tid<64 only)
    const int c0 = tid, li0 = c0 / HWF, lj0 = c0 - li0 * HWF;
    const int fiA = fi0 + li0, fjA = fj0 + lj0;
    const bool inG0 = (fiA >= 0 && fiA < 513 && fjA >= 0 && fjA < 513);
    const bool has1 = (tid < 64);
    const int c1 = tid + 512, li1 = c1 / HWF, lj1 = c1 - li1 * HWF;
    const int fiB = fi0 + li1, fjB = fj0 + lj1;
    const bool inG1 = has1 && (fiB >= 0 && fiB < 513 && fjB >= 0 && fjB < 513);

    float occ0, occ1; u8 rw0, rw1; bool cal0, cal1;
    upsample_cell(fiA, fjA, inG0, occP, calcP, occ0, rw0, cal0);
    upsample_cell(fiB, fjB, inG1, occP, calcP, occ1, rw1, cal1);
    sRaw[c0] = rw0; sOccS[c0] = occ0; sCalS[c0] = cal0 ? 1 : 0;
    sCfA[c0] = 0; sCfB[c0] = 0;
    if (has1) {
        sRaw[c1] = rw1; sOccS[c1] = occ1; sCalS[c1] = cal1 ? 1 : 0;
        sCfA[c1] = 0; sCfB[c1] = 0;
    }

    if (!__syncthreads_or((int)(rw0 | rw1))) {
        // no boundary near this tile: q never read -> pure write-through
        // (halo cells rows 21-23 are never in the core, so only c0 writes)
        if (li0 >= 4 && li0 < 20 && lj0 >= 4 && lj0 < 20 && inG0)
            out[fiA * 513 + fjA] = occ0;
        return;
    }

    // ---- in-tile MLP eval of all 576 window cells ----
    stage_w2(W2, sW2T, tid, 512);
    __syncthreads();

    const int w = tid >> 6, lane = tid & 63;   // 8 waves
    const int l15 = lane & 15, lg = lane >> 4;
    const float inv = 1.0f / 512.0f;
    const float bx0 = bmin[0], by0 = bmin[1];
    const float sx = bmax[0] - bx0, sy = bmax[1] - by0;
    const float b3v = b3[0];

    {   // call 0: cells [0, 256)
        float xs[2], ys[2];
        #pragma unroll
        for (int mf = 0; mf < 2; ++mf) {
            int cell = w * 32 + mf * 16 + l15;
            int gi = fi0 + cell / 24, gj = fj0 + cell % 24;
            gi = gi < 0 ? 0 : (gi > 512 ? 512 : gi);
            gj = gj < 0 ? 0 : (gj > 512 ? 512 : gj);
            xs[mf] = bx0 + (float)gj * inv * sx;
            ys[mf] = by0 + (float)gi * inv * sy;
        }
        float rs[2][4];
        mlp_wave(xs, ys, sW2T, W1, b1, b2, W3, lg, l15, rs);
        if (l15 == 0) {
            #pragma unroll
            for (int mf = 0; mf < 2; ++mf)
                #pragma unroll
                for (int rg = 0; rg < 4; ++rg)
                    sQ[w * 32 + mf * 16 + lg * 4 + rg] = fast_sigmoid(rs[mf][rg] + b3v);
        }
    }
    {   // call 1: cells [256, 512)
        float xs[2], ys[2];
        #pragma unroll
        for (int mf = 0; mf < 2; ++mf) {
            int cell = 256 + w * 32 + mf * 16 + l15;
            int gi = fi0 + cell / 24, gj = fj0 + cell % 24;
            gi = gi < 0 ? 0 : (gi > 512 ? 512 : gi);
            gj = gj < 0 ? 0 : (gj > 512 ? 512 : gj);
            xs[mf] = bx0 + (float)gj * inv * sx;
            ys[mf] = by0 + (float)gi * inv * sy;
        }
        float rs[2][4];
        mlp_wave(xs, ys, sW2T, W1, b1, b2, W3, lg, l15, rs);
        if (l15 == 0) {
            #pragma unroll
            for (int mf = 0; mf < 2; ++mf)
                #pragma unroll
                for (int rg = 0; rg < 4; ++rg)
                    sQ[256 + w * 32 + mf * 16 + lg * 4 + rg] = fast_sigmoid(rs[mf][rg] + b3v);
        }
    }
    if (w < 2) {   // call 2: cells [512, 576) -- waves 0,1 only, no barriers inside
        float xs[2], ys[2];
        #pragma unroll
        for (int mf = 0; mf < 2; ++mf) {
            int cell = 512 + w * 32 + mf * 16 + l15;
            int gi = fi0 + cell / 24, gj = fj0 + cell % 24;
            gi = gi < 0 ? 0 : (gi > 512 ? 512 : gi);
            gj = gj < 0 ? 0 : (gj > 512 ? 512 : gj);
            xs[mf] = bx0 + (float)gj * inv * sx;
            ys[mf] = by0 + (float)gi * inv * sy;
        }
        float rs[2][4];
        mlp_wave(xs, ys, sW2T, W1, b1, b2, W3, lg, l15, rs);
        if (l15 == 0) {
            #pragma unroll
            for (int mf = 0; mf < 2; ++mf)
                #pragma unroll
                for (int rg = 0; rg < 4; ++rg)
                    sQ[512 + w * 32 + mf * 16 + lg * 4 + rg] = fast_sigmoid(rs[mf][rg] + b3v);
        }
    }
    __syncthreads();

    // reload cell state; resolve boundary + 3 conflict iterations
    occ0 = sOccS[c0]; cal0 = sCalS[c0] != 0;
    const float qv0 = sQ[c0];
    float qv1 = 0.5f;
    if (has1) { occ1 = sOccS[c1]; cal1 = sCalS[c1] != 0; qv1 = sQ[c1]; }

    {
        u8 cf0 = 0, cf1 = 0;
        if (li0 >= 1 && li0 < HWF - 1 && lj0 >= 1 && lj0 < HWF - 1 && inG0) {
            bool b = false;
            #pragma unroll
            for (int di = -1; di <= 1; ++di)
                #pragma unroll
                for (int dj = -1; dj <= 1; ++dj)
                    if (sRaw[(li0 + di) * HWF + (lj0 + dj)]) b = true;
            b = b && !cal0;
            cf0 = (b && (occ0 - BAL) * (qv0 - BAL) < 0.0f) ? 1 : 0;
            if (b) { occ0 = qv0; cal0 = true; }
            sCfA[c0] = cf0;
        }
        if (has1 && li1 >= 1 && li1 < HWF - 1 && lj1 >= 1 && lj1 < HWF - 1 && inG1) {
            bool b = false;
            #pragma unroll
            for (int di = -1; di <= 1; ++di)
                #pragma unroll
                for (int dj = -1; dj <= 1; ++dj)
                    if (sRaw[(li1 + di) * HWF + (lj1 + dj)]) b = true;
            b = b && !cal1;
            cf1 = (b && (occ1 - BAL) * (qv1 - BAL) < 0.0f) ? 1 : 0;
            if (b) { occ1 = qv1; cal1 = true; }
            sCfA[c1] = cf1;
        }
        int haveCf = __syncthreads_or((int)(cf0 | cf1));

        #pragma unroll
        for (int it = 0; it < 3; ++it) {
            if (!haveCf) break;
            const u8* cin = (it & 1) ? sCfB : sCfA;
            u8* cout      = (it & 1) ? sCfA : sCfB;
            int lo = 2 + it, hi = HWF - 2 - it;
            u8 nc0 = 0, nc1 = 0;
            if (li0 >= lo && li0 < hi && lj0 >= lo && lj0 < hi && inG0) {
                bool any = false;
                #pragma unroll
                for (int di = -1; di <= 1; ++di)
                    #pragma unroll
                    for (int dj = -1; dj <= 1; ++dj)
                        if (cin[(li0 + di) * HWF + (lj0 + dj)]) any = true;
                bool cand = any && !cal0;
                nc0 = (cand && (occ0 - BAL) * (qv0 - BAL) < 0.0f) ? 1 : 0;
                if (cand) { occ0 = qv0; cal0 = true; }
                cout[c0] = nc0;
            }
            if (has1 && li1 >= lo && li1 < hi && lj1 >= lo && lj1 < hi && inG1) {
                bool any = false;
                #pragma unroll
                for (int di = -1; di <= 1; ++di)
                    #pragma unroll
                    for (int dj = -1; dj <= 1; ++dj)
                        if (cin[(li1 + di) * HWF + (lj1 + dj)]) any = true;
                bool cand = any && !cal1;
                nc1 = (cand && (occ1 - BAL) * (qv1 - BAL) < 0.0f) ? 1 : 0;
                if (cand) { occ1 = qv1; cal1 = true; }
                cout[c1] = nc1;
            }
            haveCf = __syncthreads_or((int)(nc0 | nc1));
        }
    }

    if (li0 >= 4 && li0 < 20 && lj0 >= 4 && lj0 < 20 && inG0)
        out[fiA * 513 + fjA] = occ0;
}

extern "C" void kernel_launch(void* const* d_in, const int* in_sizes, int n_in,
                              void* d_out, int out_size, void* d_ws, size_t ws_size,
                              hipStream_t stream) {
    const float* W1   = (const float*)d_in[0];
    const float* b1   = (const float*)d_in[1];
    const float* W2   = (const float*)d_in[2];
    const float* b2   = (const float*)d_in[3];
    const float* W3   = (const float*)d_in[4];
    const float* b3   = (const float*)d_in[5];
    const float* bmin = (const float*)d_in[6];
    const float* bmax = (const float*)d_in[7];

    const int N257 = 257 * 257;
    float* q257   = (float*)d_ws;
    float* occ257 = q257 + N257;
    u8*    cal257 = (u8*)(occ257 + N257);
    float* out    = (float*)d_out;

    // 1) dense eval at 257 (covers all q-reads of levels 1-3 bit-exactly)
    eval_grid<<<(N257 + TM - 1) / TM, 256, 0, stream>>>(
        W1, b1, W2, b2, W3, b3, bmin, bmax, q257, 257);

    // 2) levels 1-3 fused -> refined occ257 + cal257
    levels123_fused<<<17 * 17, NTF, 0, stream>>>(q257, occ257, cal257);

    // 3) level 4 with in-tile masked fine eval -> output
    level4_fused<<<33 * 33, 512, 0, stream>>>(
        W1, b1, W2, b2, W3, b3, bmin, bmax, occ257, cal257, out);
}

// Round 23
// 45.883 us; speedup vs baseline: 3.1200x; 3.1200x over previous
//
#include <hip/hip_runtime.h>

typedef unsigned char u8;
typedef float f32x4 __attribute__((ext_vector_type(4)));
typedef _Float16 f16x8 __attribute__((ext_vector_type(8)));

#define DIM 128
#define TM  128
// Spill rules (r17/r20/r21/r22, measured): (a) never wrap the MFMA block in a
// runtime loop; (b) never put MORE THAN ONE mlp_wave call in a kernel -- the
// compiler merges the MFMA live sets and spills ~40-60MB to scratch; (c) MFMA
// kernels at 4- or 8-wave blocks with __launch_bounds__(N,4) only.

__device__ __forceinline__ float fast_tanh(float x) {
    // tanh(x) = 1 - 2/(exp2(2x*log2e)+1); exact +-1 saturation via inf->0
    float e = __builtin_amdgcn_exp2f(x * 2.885390081777927f);
    return 1.0f - 2.0f * __builtin_amdgcn_rcpf(e + 1.0f);
}
__device__ __forceinline__ float fast_sigmoid(float x) {
    float e = __builtin_amdgcn_exp2f(x * -1.4426950408889634f);
    return __builtin_amdgcn_rcpf(1.0f + e);
}

// stage W2^T (fp16, XOR-swizzled 16B chunks) into LDS
template<int NT>
__device__ __forceinline__ void stage_w2(const float* __restrict__ W2,
                                         _Float16* sW2T, int tid) {
    #pragma unroll
    for (int s = 0; s < 2048 / NT; ++s) {
        int chunk = s * NT + tid;        // 0..2047
        int n = chunk & 127, ko = chunk >> 7;
        f16x8 v;
        #pragma unroll
        for (int qq = 0; qq < 8; ++qq)
            v[qq] = (_Float16)W2[(ko * 8 + qq) * DIM + n];   // coalesced over n
        int slot = ko ^ (n & 15);
        *(f16x8*)&sW2T[n * DIM + slot * 8] = v;
    }
}

// one wave: 32 points (2 A-frags) x 128 dims; b2 folded into acc init.
// rs[mf][rg] = sum_c tanh(h2)*W3, lane-reduced (valid on all lanes).
// C/D: point-row = mf*16 + lg*4 + rg.
__device__ __forceinline__ void mlp_wave(
    const float xs[2], const float ys[2], const _Float16* sW2T,
    const float* __restrict__ W1, const float* __restrict__ b1,
    const float* __restrict__ b2, const float* __restrict__ W3,
    int lg, int l15, float rs[2][4])
{
    f32x4 acc[2][8];
    #pragma unroll
    for (int nf = 0; nf < 8; ++nf) {
        float b2v = b2[nf * 16 + l15];
        acc[0][nf] = (f32x4)(b2v);
        acc[1][nf] = (f32x4)(b2v);
    }
    #pragma unroll
    for (int kf = 0; kf < 4; ++kf) {
        const int kbase = kf * 32 + lg * 8;
        f16x8 bh[8];
        #pragma unroll
        for (int nf = 0; nf < 8; ++nf) {
            int cc = nf * 16 + l15;
            int slot = (kf * 4 + lg) ^ l15;   // matches stage_w2 swizzle
            bh[nf] = *(const f16x8*)&sW2T[cc * DIM + slot * 8];
        }
        f32x4 wxa = *(const f32x4*)&W1[kbase];
        f32x4 wxb = *(const f32x4*)&W1[kbase + 4];
        f32x4 wya = *(const f32x4*)&W1[DIM + kbase];
        f32x4 wyb = *(const f32x4*)&W1[DIM + kbase + 4];
        f32x4 b1a = *(const f32x4*)&b1[kbase];
        f32x4 b1b = *(const f32x4*)&b1[kbase + 4];
        f16x8 ah[2];
        #pragma unroll
        for (int mf = 0; mf < 2; ++mf) {
            float x = xs[mf], y = ys[mf];
            #pragma unroll
            for (int qq = 0; qq < 4; ++qq)
                ah[mf][qq] = (_Float16)fast_tanh(fmaf(x, wxa[qq], fmaf(y, wya[qq], b1a[qq])));
            #pragma unroll
            for (int qq = 0; qq < 4; ++qq)
                ah[mf][4 + qq] = (_Float16)fast_tanh(fmaf(x, wxb[qq], fmaf(y, wyb[qq], b1b[qq])));
        }
        #pragma unroll
        for (int nf = 0; nf < 8; ++nf)
            #pragma unroll
            for (int mf = 0; mf < 2; ++mf)
                acc[mf][nf] = __builtin_amdgcn_mfma_f32_16x16x32_f16(ah[mf], bh[nf], acc[mf][nf], 0, 0, 0);
    }
    #pragma unroll
    for (int mf = 0; mf < 2; ++mf)
        #pragma unroll
        for (int rg = 0; rg < 4; ++rg) rs[mf][rg] = 0.0f;
    #pragma unroll
    for (int nf = 0; nf < 8; ++nf) {
        float w3v = W3[nf * 16 + l15];
        #pragma unroll
        for (int mf = 0; mf < 2; ++mf)
            #pragma unroll
            for (int rg = 0; rg < 4; ++rg)
                rs[mf][rg] += fast_tanh(acc[mf][nf][rg]) * w3v;
    }
    #pragma unroll
    for (int mf = 0; mf < 2; ++mf)
        #pragma unroll
        for (int rg = 0; rg < 4; ++rg) {
            float v = rs[mf][rg];
            v += __shfl_xor(v, 1);
            v += __shfl_xor(v, 2);
            v += __shfl_xor(v, 4);
            v += __shfl_xor(v, 8);
            rs[mf][rg] = v;
        }
}

// ---- dense MLP eval of an RxR grid (R-1 power of two); straight-line ----
__global__ __launch_bounds__(256, 4) void eval_grid(
    const float* __restrict__ W1, const float* __restrict__ b1,
    const float* __restrict__ W2, const float* __restrict__ b2,
    const float* __restrict__ W3, const float* __restrict__ b3,
    const float* __restrict__ bmin, const float* __restrict__ bmax,
    float* __restrict__ out, int R)
{
    __shared__ __align__(16) _Float16 sW2T[DIM * DIM];   // 32 KB
    const int N = R * R;
    const int tid = threadIdx.x;
    const int m0 = blockIdx.x * TM;
    stage_w2<256>(W2, sW2T, tid);

    const int w = tid >> 6, lane = tid & 63;
    const int l15 = lane & 15, lg = lane >> 4;

    const float inv = 1.0f / (float)(R - 1);   // power-of-two -> exact
    const float bx0 = bmin[0], by0 = bmin[1];
    const float sx = bmax[0] - bx0, sy = bmax[1] - by0;
    float xs[2], ys[2];
    #pragma unroll
    for (int mf = 0; mf < 2; ++mf) {
        int pi = m0 + w * 32 + mf * 16 + l15;
        int pg = (pi < N) ? pi : N - 1;
        int gi = pg / R, gj = pg - gi * R;
        xs[mf] = bx0 + (float)gj * inv * sx;
        ys[mf] = by0 + (float)gi * inv * sy;
    }
    __syncthreads();

    float rs[2][4];
    mlp_wave(xs, ys, sW2T, W1, b1, b2, W3, lg, l15, rs);
    if (l15 == 0) {
        float b3v = b3[0];
        #pragma unroll
        for (int mf = 0; mf < 2; ++mf)
            #pragma unroll
            for (int rg = 0; rg < 4; ++rg) {
                int po = m0 + w * 32 + mf * 16 + lg * 4 + rg;
                if (po < N) out[po] = fast_sigmoid(rs[mf][rg] + b3v);
            }
    }
}

// ---- masked fine eval of the 513 grid: one 16x16 tile per block, 512 thr ----
// Exit unless raw4 (from refined occ257) exists in the +-4-expanded box --
// superset of all q-reads of level 4. 8 waves x 32 pts = 256 pts, ONE
// straight-line mlp_wave call (no loop, single call -> no scratch spill).
__global__ __launch_bounds__(512, 4) void eval_fine(
    const float* __restrict__ W1, const float* __restrict__ b1,
    const float* __restrict__ W2, const float* __restrict__ b2,
    const float* __restrict__ W3, const float* __restrict__ b3,
    const float* __restrict__ bmin, const float* __restrict__ bmax,
    const float* __restrict__ occ3, float* __restrict__ q4)
{
    __shared__ __align__(16) _Float16 sW2T[DIM * DIM];
    const int bi = blockIdx.x / 33, bj = blockIdx.x - bi * 33;  // 33x33 tiles
    const int ti0 = bi * 16, tj0 = bj * 16;
    const int tid = threadIdx.x;

    bool need = false;
    for (int s = tid; s < 576; s += 512) {     // no MFMA state live here
        int li = s / 24, lj = s - li * 24;
        int fi = ti0 - 4 + li, fj = tj0 - 4 + lj;
        if (fi >= 0 && fi < 513 && fj >= 0 && fj < 513) {
            int oi = fi & 1, oj = fj & 1;
            if (oi | oj) {
                int ip = fi >> 1, jp = fj >> 1;
                bool m0 = occ3[ip * 257 + jp] > 0.5f;
                bool b;
                if (oi && !oj)      b = m0 != (occ3[(ip + 1) * 257 + jp] > 0.5f);
                else if (!oi && oj) b = m0 != (occ3[ip * 257 + jp + 1] > 0.5f);
                else {
                    bool m1 = occ3[(ip + 1) * 257 + jp] > 0.5f;
                    bool m2 = occ3[ip * 257 + jp + 1] > 0.5f;
                    bool m3 = occ3[(ip + 1) * 257 + jp + 1] > 0.5f;
                    b = (m0 | m1 | m2 | m3) && !(m0 & m1 & m2 & m3);
                }
                need |= b;
            }
        }
    }
    if (!__syncthreads_or(need ? 1 : 0)) return;

    stage_w2<512>(W2, sW2T, tid);
    __syncthreads();

    const int w = tid >> 6, lane = tid & 63;
    const int l15 = lane & 15, lg = lane >> 4;
    const float inv = 1.0f / 512.0f;
    const float bx0 = bmin[0], by0 = bmin[1];
    const float sx = bmax[0] - bx0, sy = bmax[1] - by0;

    float xs[2], ys[2];
    #pragma unroll
    for (int mf = 0; mf < 2; ++mf) {
        int p = w * 32 + mf * 16 + l15;        // 0..255 within tile
        int gi = ti0 + (p >> 4), gj = tj0 + (p & 15);
        if (gi > 512) gi = 512;
        if (gj > 512) gj = 512;
        xs[mf] = bx0 + (float)gj * inv * sx;
        ys[mf] = by0 + (float)gi * inv * sy;
    }
    float rs[2][4];
    mlp_wave(xs, ys, sW2T, W1, b1, b2, W3, lg, l15, rs);
    if (l15 == 0) {
        float b3v = b3[0];
        #pragma unroll
        for (int mf = 0; mf < 2; ++mf)
            #pragma unroll
            for (int rg = 0; rg < 4; ++rg) {
                int p = w * 32 + mf * 16 + lg * 4 + rg;
                int gi = ti0 + (p >> 4), gj = tj0 + (p & 15);
                if (gi < 513 && gj < 513)
                    q4[gi * 513 + gj] = fast_sigmoid(rs[mf][rg] + b3v);
            }
    }
}

// ---- one refinement level on a 24x24 window, one thread per cell ----
#define HWF 24
#define NTF 576
template<bool FIRST>
__device__ __forceinline__ void run_level(
    int c, int li, int lj, int oi0, int oj0, int R,
    const float* __restrict__ qbuf, int qpitch, int qs,
    const float* __restrict__ q257, int pOi, int pOj,
    const float* sOccP, const u8* sCalP,
    u8* sRaw, u8* sCfA, u8* sCfB,
    float& occR, bool& calR)
{
    const float BAL = 0.5f;
    const int fi = oi0 + li, fj = oj0 + lj;
    const bool inG = (fi >= 0 && fi < R && fj >= 0 && fj < R);
    float occ = 0.5f, qv = 0.5f;
    u8 rw = 0; bool cal = false;
    if (inG) qv = qbuf[(fi * qs) * qpitch + fj * qs];   // issued early, used late
    if (inG) {
        int ip = fi >> 1, jp = fj >> 1;
        int oi = fi & 1, oj = fj & 1;
        float tl = FIRST ? q257[(ip * 8) * 257 + jp * 8]
                         : sOccP[(ip - pOi) * HWF + (jp - pOj)];
        bool b;
        if (!oi && !oj) { occ = tl; b = false; }
        else if (oi && !oj) {
            float bl = FIRST ? q257[((ip + 1) * 8) * 257 + jp * 8]
                             : sOccP[(ip + 1 - pOi) * HWF + (jp - pOj)];
            occ = 0.5f * (tl + bl);
            b = (tl > BAL) != (bl > BAL);
        } else if (!oi && oj) {
            float tr = FIRST ? q257[(ip * 8) * 257 + (jp + 1) * 8]
                             : sOccP[(ip - pOi) * HWF + (jp + 1 - pOj)];
            occ = 0.5f * (tl + tr);
            b = (tl > BAL) != (tr > BAL);
        } else {
            float bl = FIRST ? q257[((ip + 1) * 8) * 257 + jp * 8]
                             : sOccP[(ip + 1 - pOi) * HWF + (jp - pOj)];
            float tr = FIRST ? q257[(ip * 8) * 257 + (jp + 1) * 8]
                             : sOccP[(ip - pOi) * HWF + (jp + 1 - pOj)];
            float br = FIRST ? q257[((ip + 1) * 8) * 257 + (jp + 1) * 8]
                             : sOccP[(ip + 1 - pOi) * HWF + (jp + 1 - pOj)];
            occ = 0.5f * (0.5f * (tl + bl) + 0.5f * (tr + br));  // exact _up2 order
            bool m0 = tl > BAL, m1 = bl > BAL, m2 = tr > BAL, m3 = br > BAL;
            b = (m0 | m1 | m2 | m3) && !(m0 & m1 & m2 & m3);
        }
        rw = b ? 1 : 0;
        if (((fi | fj) & 1) == 0)
            cal = FIRST ? true : (sCalP[(ip - pOi) * HWF + (jp - pOj)] != 0);
    }
    sRaw[c] = rw; sCfA[c] = 0; sCfB[c] = 0;

    if (__syncthreads_or(rw)) {
        u8 cf = 0;
        if (li >= 1 && li < HWF - 1 && lj >= 1 && lj < HWF - 1 && inG) {
            bool b = false;
            #pragma unroll
            for (int di = -1; di <= 1; ++di)
                #pragma unroll
                for (int dj = -1; dj <= 1; ++dj)
                    if (sRaw[(li + di) * HWF + (lj + dj)]) b = true;
            b = b && !cal;
            cf = (b && (occ - BAL) * (qv - BAL) < 0.0f) ? 1 : 0;
            if (b) { occ = qv; cal = true; }
            sCfA[c] = cf;
        }
        int haveCf = __syncthreads_or((int)cf);

        #pragma unroll
        for (int it = 0; it < 3; ++it) {
            if (!haveCf) break;
            const u8* cin = (it & 1) ? sCfB : sCfA;
            u8* cout      = (it & 1) ? sCfA : sCfB;
            int lo = 2 + it, hi = HWF - 2 - it;
            u8 nc = 0;
            if (li >= lo && li < hi && lj >= lo && lj < hi && inG) {
                bool any = false;
                #pragma unroll
                for (int di = -1; di <= 1; ++di)
                    #pragma unroll
                    for (int dj = -1; dj <= 1; ++dj)
                        if (cin[(li + di) * HWF + (lj + dj)]) any = true;
                bool cand = any && !cal;
                nc = (cand && (occ - BAL) * (qv - BAL) < 0.0f) ? 1 : 0;
                if (cand) { occ = qv; cal = true; }
                cout[c] = nc;
            }
            haveCf = __syncthreads_or((int)nc);
        }
    }
    occR = occ; calR = cal;
}

// ---- levels 1-3 fused, one block per 16x16 tile of the 257 grid ----
// Origins: o3=16b-4 (257), o2=8b-6 (129), o1=4b-7 (65); each level's parent
// reads land inside the previous window's exact core [4,20).
__global__ __launch_bounds__(NTF) void levels123_fused(
    const float* __restrict__ q257,
    float* __restrict__ occ257, u8* __restrict__ cal257)
{
    __shared__ float sOcc[NTF];
    __shared__ u8 sCal[NTF], sRaw[NTF], sCfA[NTF], sCfB[NTF];
    const int bi = blockIdx.x / 17, bj = blockIdx.x - bi * 17;
    const int c = threadIdx.x;
    const int li = c / HWF, lj = c - li * HWF;
    float occ; bool cal;

    run_level<true>(c, li, lj, 4 * bi - 7, 4 * bj - 7, 65,
                    q257, 257, 4, q257, 0, 0,
                    sOcc, sCal, sRaw, sCfA, sCfB, occ, cal);
    sOcc[c] = occ; sCal[c] = cal ? 1 : 0;
    __syncthreads();
    run_level<false>(c, li, lj, 8 * bi - 6, 8 * bj - 6, 129,
                     q257, 257, 2, q257, 4 * bi - 7, 4 * bj - 7,
                     sOcc, sCal, sRaw, sCfA, sCfB, occ, cal);
    sOcc[c] = occ; sCal[c] = cal ? 1 : 0;
    __syncthreads();
    run_level<false>(c, li, lj, 16 * bi - 4, 16 * bj - 4, 257,
                     q257, 257, 1, q257, 8 * bi - 6, 8 * bj - 6,
                     sOcc, sCal, sRaw, sCfA, sCfB, occ, cal);

    const int fi = 16 * bi - 4 + li, fj = 16 * bj - 4 + lj;
    if (li >= 4 && li < 20 && lj >= 4 && lj < 20 && fi < 257 && fj < 257) {
        occ257[fi * 257 + fj] = occ;
        cal257[fi * 257 + fj] = cal ? 1 : 0;
    }
}

// ---- level 4 standalone: one block per 16x16 tile of 513, global parents ----
__global__ __launch_bounds__(NTF) void level4_kernel(
    const float* __restrict__ occP, const u8* __restrict__ calcP,
    const float* __restrict__ q4, float* __restrict__ out)
{
    __shared__ u8 sRaw[NTF], sCfA[NTF], sCfB[NTF];
    const int bi = blockIdx.x / 33, bj = blockIdx.x - bi * 33;
    const int fi0 = bi * 16 - 4, fj0 = bj * 16 - 4;
    const int c = threadIdx.x;
    const int li = c / HWF, lj = c - li * HWF;
    const int fi = fi0 + li, fj = fj0 + lj;
    const bool inG = (fi >= 0 && fi < 513 && fj >= 0 && fj < 513);
    const float BAL = 0.5f;

    float occ = 0.5f, qv = 0.5f;
    u8 rw = 0; bool cal = false;
    if (inG) qv = q4[fi * 513 + fj];      // issued early, used late
    if (inG) {
        int ip = fi >> 1, jp = fj >> 1;
        float tl = occP[ip * 257 + jp];
        int oi = fi & 1, oj = fj & 1;
        bool b;
        if (!oi && !oj) { occ = tl; b = false; }
        else if (oi && !oj) {
            float bl = occP[(ip + 1) * 257 + jp];
            occ = 0.5f * (tl + bl);
            b = (tl > BAL) != (bl > BAL);
        } else if (!oi && oj) {
            float tr = occP[ip * 257 + jp + 1];
            occ = 0.5f * (tl + tr);
            b = (tl > BAL) != (tr > BAL);
        } else {
            float bl = occP[(ip + 1) * 257 + jp];
            float tr = occP[ip * 257 + jp + 1];
            float br = occP[(ip + 1) * 257 + jp + 1];
            occ = 0.5f * (0.5f * (tl + bl) + 0.5f * (tr + br));  // exact _up2 order
            bool m0 = tl > BAL, m1 = bl > BAL, m2 = tr > BAL, m3 = br > BAL;
            b = (m0 | m1 | m2 | m3) && !(m0 & m1 & m2 & m3);
        }
        rw = b ? 1 : 0;
        if (((fi | fj) & 1) == 0) cal = calcP[ip * 257 + jp] != 0;
    }
    sRaw[c] = rw; sCfA[c] = 0; sCfB[c] = 0;

    if (__syncthreads_or(rw)) {
        u8 cf = 0;
        if (li >= 1 && li < HWF - 1 && lj >= 1 && lj < HWF - 1 && inG) {
            bool b = false;
            #pragma unroll
            for (int di = -1; di <= 1; ++di)
                #pragma unroll
                for (int dj = -1; dj <= 1; ++dj)
                    if (sRaw[(li + di) * HWF + (lj + dj)]) b = true;
            b = b && !cal;
            cf = (b && (occ - BAL) * (qv - BAL) < 0.0f) ? 1 : 0;
            if (b) { occ = qv; cal = true; }
            sCfA[c] = cf;
        }
        int haveCf = __syncthreads_or((int)cf);

        #pragma unroll
        for (int it = 0; it < 3; ++it) {
            if (!haveCf) break;
            const u8* cin = (it & 1) ? sCfB : sCfA;
            u8* cout      = (it & 1) ? sCfA : sCfB;
            int lo = 2 + it, hi = HWF - 2 - it;
            u8 nc = 0;
            if (li >= lo && li < hi && lj >= lo && lj < hi && inG) {
                bool any = false;
                #pragma unroll
                for (int di = -1; di <= 1; ++di)
                    #pragma unroll
                    for (int dj = -1; dj <= 1; ++dj)
                        if (cin[(li + di) * HWF + (lj + dj)]) any = true;
                bool cand = any && !cal;
                nc = (cand && (occ - BAL) * (qv - BAL) < 0.0f) ? 1 : 0;
                if (cand) { occ = qv; cal = true; }
                cout[c] = nc;
            }
            haveCf = __syncthreads_or((int)nc);
        }
    }

    if (li >= 4 && li < 20 && lj >= 4 && lj < 20 && inG)
        out[fi * 513 + fj] = occ;
}

extern "C" void kernel_launch(void* const* d_in, const int* in_sizes, int n_in,
                              void* d_out, int out_size, void* d_ws, size_t ws_size,
                              hipStream_t stream) {
    const float* W1   = (const float*)d_in[0];
    const float* b1   = (const float*)d_in[1];
    const float* W2   = (const float*)d_in[2];
    const float* b2   = (const float*)d_in[3];
    const float* W3   = (const float*)d_in[4];
    const float* b3   = (const float*)d_in[5];
    const float* bmin = (const float*)d_in[6];
    const float* bmax = (const float*)d_in[7];

    const int N513 = 513 * 513, N257 = 257 * 257;
    float* q257   = (float*)d_ws;
    float* occ257 = q257 + N257;
    float* q4     = occ257 + N257;
    u8*    cal257 = (u8*)(q4 + N513);
    float* out    = (float*)d_out;

    // 1) dense eval at 257 (covers all q-reads of levels 1-3 bit-exactly)
    eval_grid<<<(N257 + TM - 1) / TM, 256, 0, stream>>>(
        W1, b1, W2, b2, W3, b3, bmin, bmax, q257, 257);

    // 2) levels 1-3 fused -> refined occ257 + cal257
    levels123_fused<<<17 * 17, NTF, 0, stream>>>(q257, occ257, cal257);

    // 3) masked fine eval of the 513 grid (only boundary-adjacent tiles)
    eval_fine<<<33 * 33, 512, 0, stream>>>(
        W1, b1, W2, b2, W3, b3, bmin, bmax, occ257, q4);

    // 4) level 4 -> output
    level4_kernel<<<33 * 33, NTF, 0, stream>>>(occ257, cal257, q4, out);
}

// Round 24
// 43.303 us; speedup vs baseline: 3.3058x; 1.0596x over previous
//
#include <hip/hip_runtime.h>

typedef unsigned char u8;
typedef float f32x4 __attribute__((ext_vector_type(4)));
typedef _Float16 f16x8 __attribute__((ext_vector_type(8)));

#define DIM 128
#define TM  128
// Spill rules (r17/r20/r21/r22, measured): (a) never wrap the MFMA block in a
// runtime loop; (b) never put MORE THAN ONE mlp_wave call in a kernel -- the
// compiler merges the MFMA live sets and spills ~40-60MB to scratch; (c) MFMA
// kernels at 4- or 8-wave blocks with __launch_bounds__(N,4) only.

__device__ __forceinline__ float fast_tanh(float x) {
    // tanh(x) = 1 - 2/(exp2(2x*log2e)+1); exact +-1 saturation via inf->0
    float e = __builtin_amdgcn_exp2f(x * 2.885390081777927f);
    return 1.0f - 2.0f * __builtin_amdgcn_rcpf(e + 1.0f);
}
__device__ __forceinline__ float fast_sigmoid(float x) {
    float e = __builtin_amdgcn_exp2f(x * -1.4426950408889634f);
    return __builtin_amdgcn_rcpf(1.0f + e);
}

// stage W2^T (fp16, XOR-swizzled 16B chunks) into LDS
template<int NT>
__device__ __forceinline__ void stage_w2(const float* __restrict__ W2,
                                         _Float16* sW2T, int tid) {
    #pragma unroll
    for (int s = 0; s < 2048 / NT; ++s) {
        int chunk = s * NT + tid;        // 0..2047
        int n = chunk & 127, ko = chunk >> 7;
        f16x8 v;
        #pragma unroll
        for (int qq = 0; qq < 8; ++qq)
            v[qq] = (_Float16)W2[(ko * 8 + qq) * DIM + n];   // coalesced over n
        int slot = ko ^ (n & 15);
        *(f16x8*)&sW2T[n * DIM + slot * 8] = v;
    }
}

// one wave: 32 points (2 A-frags) x 128 dims; b2 folded into acc init.
// rs[mf][rg] = sum_c tanh(h2)*W3, lane-reduced (valid on all lanes).
// C/D: point-row = mf*16 + lg*4 + rg.
__device__ __forceinline__ void mlp_wave(
    const float xs[2], const float ys[2], const _Float16* sW2T,
    const float* __restrict__ W1, const float* __restrict__ b1,
    const float* __restrict__ b2, const float* __restrict__ W3,
    int lg, int l15, float rs[2][4])
{
    f32x4 acc[2][8];
    #pragma unroll
    for (int nf = 0; nf < 8; ++nf) {
        float b2v = b2[nf * 16 + l15];
        acc[0][nf] = (f32x4)(b2v);
        acc[1][nf] = (f32x4)(b2v);
    }
    #pragma unroll
    for (int kf = 0; kf < 4; ++kf) {
        const int kbase = kf * 32 + lg * 8;
        f16x8 bh[8];
        #pragma unroll
        for (int nf = 0; nf < 8; ++nf) {
            int cc = nf * 16 + l15;
            int slot = (kf * 4 + lg) ^ l15;   // matches stage_w2 swizzle
            bh[nf] = *(const f16x8*)&sW2T[cc * DIM + slot * 8];
        }
        f32x4 wxa = *(const f32x4*)&W1[kbase];
        f32x4 wxb = *(const f32x4*)&W1[kbase + 4];
        f32x4 wya = *(const f32x4*)&W1[DIM + kbase];
        f32x4 wyb = *(const f32x4*)&W1[DIM + kbase + 4];
        f32x4 b1a = *(const f32x4*)&b1[kbase];
        f32x4 b1b = *(const f32x4*)&b1[kbase + 4];
        f16x8 ah[2];
        #pragma unroll
        for (int mf = 0; mf < 2; ++mf) {
            float x = xs[mf], y = ys[mf];
            #pragma unroll
            for (int qq = 0; qq < 4; ++qq)
                ah[mf][qq] = (_Float16)fast_tanh(fmaf(x, wxa[qq], fmaf(y, wya[qq], b1a[qq])));
            #pragma unroll
            for (int qq = 0; qq < 4; ++qq)
                ah[mf][4 + qq] = (_Float16)fast_tanh(fmaf(x, wxb[qq], fmaf(y, wyb[qq], b1b[qq])));
        }
        #pragma unroll
        for (int nf = 0; nf < 8; ++nf)
            #pragma unroll
            for (int mf = 0; mf < 2; ++mf)
                acc[mf][nf] = __builtin_amdgcn_mfma_f32_16x16x32_f16(ah[mf], bh[nf], acc[mf][nf], 0, 0, 0);
    }
    #pragma unroll
    for (int mf = 0; mf < 2; ++mf)
        #pragma unroll
        for (int rg = 0; rg < 4; ++rg) rs[mf][rg] = 0.0f;
    #pragma unroll
    for (int nf = 0; nf < 8; ++nf) {
        float w3v = W3[nf * 16 + l15];
        #pragma unroll
        for (int mf = 0; mf < 2; ++mf)
            #pragma unroll
            for (int rg = 0; rg < 4; ++rg)
                rs[mf][rg] += fast_tanh(acc[mf][nf][rg]) * w3v;
    }
    #pragma unroll
    for (int mf = 0; mf < 2; ++mf)
        #pragma unroll
        for (int rg = 0; rg < 4; ++rg) {
            float v = rs[mf][rg];
            v += __shfl_xor(v, 1);
            v += __shfl_xor(v, 2);
            v += __shfl_xor(v, 4);
            v += __shfl_xor(v, 8);
            rs[mf][rg] = v;
        }
}

// ---- dense MLP eval of an RxR grid (R-1 power of two); straight-line ----
__global__ __launch_bounds__(256, 4) void eval_grid(
    const float* __restrict__ W1, const float* __restrict__ b1,
    const float* __restrict__ W2, const float* __restrict__ b2,
    const float* __restrict__ W3, const float* __restrict__ b3,
    const float* __restrict__ bmin, const float* __restrict__ bmax,
    float* __restrict__ out, int R)
{
    __shared__ __align__(16) _Float16 sW2T[DIM * DIM];   // 32 KB
    const int N = R * R;
    const int tid = threadIdx.x;
    const int m0 = blockIdx.x * TM;
    stage_w2<256>(W2, sW2T, tid);

    const int w = tid >> 6, lane = tid & 63;
    const int l15 = lane & 15, lg = lane >> 4;

    const float inv = 1.0f / (float)(R - 1);   // power-of-two -> exact
    const float bx0 = bmin[0], by0 = bmin[1];
    const float sx = bmax[0] - bx0, sy = bmax[1] - by0;
    float xs[2], ys[2];
    #pragma unroll
    for (int mf = 0; mf < 2; ++mf) {
        int pi = m0 + w * 32 + mf * 16 + l15;
        int pg = (pi < N) ? pi : N - 1;
        int gi = pg / R, gj = pg - gi * R;
        xs[mf] = bx0 + (float)gj * inv * sx;
        ys[mf] = by0 + (float)gi * inv * sy;
    }
    __syncthreads();

    float rs[2][4];
    mlp_wave(xs, ys, sW2T, W1, b1, b2, W3, lg, l15, rs);
    if (l15 == 0) {
        float b3v = b3[0];
        #pragma unroll
        for (int mf = 0; mf < 2; ++mf)
            #pragma unroll
            for (int rg = 0; rg < 4; ++rg) {
                int po = m0 + w * 32 + mf * 16 + lg * 4 + rg;
                if (po < N) out[po] = fast_sigmoid(rs[mf][rg] + b3v);
            }
    }
}

// ---- masked fine eval of the 513 grid: one 16x16 tile per block, 512 thr ----
// Need-check via sgn257 (written by levels123): the tile's window can contain
// raw4 iff the 13x13 parent sign-region [8b-2, 8b+10]^2 is NON-UNIFORM
// (connected region: non-uniform <=> adjacent differing pair => raw in/near
// window; uniform => no raw). 169 byte reads vs ~2000 float ops before.
// 8 waves x 32 pts = 256 pts, ONE straight-line mlp_wave call (no spill).
__global__ __launch_bounds__(512, 4) void eval_fine(
    const float* __restrict__ W1, const float* __restrict__ b1,
    const float* __restrict__ W2, const float* __restrict__ b2,
    const float* __restrict__ W3, const float* __restrict__ b3,
    const float* __restrict__ bmin, const float* __restrict__ bmax,
    const u8* __restrict__ sgn257, float* __restrict__ q4)
{
    __shared__ __align__(16) _Float16 sW2T[DIM * DIM];
    const int bi = blockIdx.x / 33, bj = blockIdx.x - bi * 33;  // 33x33 tiles
    const int ti0 = bi * 16, tj0 = bj * 16;
    const int tid = threadIdx.x;

    const int iLo = (8 * bi - 2) < 0 ? 0 : (8 * bi - 2);
    const int iHi = (8 * bi + 10) > 256 ? 256 : (8 * bi + 10);
    const int jLo = (8 * bj - 2) < 0 ? 0 : (8 * bj - 2);
    const int jHi = (8 * bj + 10) > 256 ? 256 : (8 * bj + 10);
    const u8 ref = sgn257[iLo * 257 + jLo];
    bool diff = false;
    for (int s = tid; s < 169; s += 512) {
        int ii = iLo + s / 13, jj = jLo + s % 13;
        if (ii <= iHi && jj <= jHi)
            diff |= (sgn257[ii * 257 + jj] != ref);
    }
    if (!__syncthreads_or(diff ? 1 : 0)) return;

    stage_w2<512>(W2, sW2T, tid);
    __syncthreads();

    const int w = tid >> 6, lane = tid & 63;
    const int l15 = lane & 15, lg = lane >> 4;
    const float inv = 1.0f / 512.0f;
    const float bx0 = bmin[0], by0 = bmin[1];
    const float sx = bmax[0] - bx0, sy = bmax[1] - by0;

    float xs[2], ys[2];
    #pragma unroll
    for (int mf = 0; mf < 2; ++mf) {
        int p = w * 32 + mf * 16 + l15;        // 0..255 within tile
        int gi = ti0 + (p >> 4), gj = tj0 + (p & 15);
        if (gi > 512) gi = 512;
        if (gj > 512) gj = 512;
        xs[mf] = bx0 + (float)gj * inv * sx;
        ys[mf] = by0 + (float)gi * inv * sy;
    }
    float rs[2][4];
    mlp_wave(xs, ys, sW2T, W1, b1, b2, W3, lg, l15, rs);
    if (l15 == 0) {
        float b3v = b3[0];
        #pragma unroll
        for (int mf = 0; mf < 2; ++mf)
            #pragma unroll
            for (int rg = 0; rg < 4; ++rg) {
                int p = w * 32 + mf * 16 + lg * 4 + rg;
                int gi = ti0 + (p >> 4), gj = tj0 + (p & 15);
                if (gi < 513 && gj < 513)
                    q4[gi * 513 + gj] = fast_sigmoid(rs[mf][rg] + b3v);
            }
    }
}

// ---- one refinement level on a 24x24 window, one thread per cell ----
#define HWF 24
#define NTF 576
template<bool FIRST>
__device__ __forceinline__ void run_level(
    int c, int li, int lj, int oi0, int oj0, int R,
    const float* __restrict__ qbuf, int qpitch, int qs,
    const float* __restrict__ q257, int pOi, int pOj,
    const float* sOccP, const u8* sCalP,
    u8* sRaw, u8* sCfA, u8* sCfB,
    float& occR, bool& calR)
{
    const float BAL = 0.5f;
    const int fi = oi0 + li, fj = oj0 + lj;
    const bool inG = (fi >= 0 && fi < R && fj >= 0 && fj < R);
    float occ = 0.5f, qv = 0.5f;
    u8 rw = 0; bool cal = false;
    if (inG) qv = qbuf[(fi * qs) * qpitch + fj * qs];   // issued early, used late
    if (inG) {
        int ip = fi >> 1, jp = fj >> 1;
        int oi = fi & 1, oj = fj & 1;
        float tl = FIRST ? q257[(ip * 8) * 257 + jp * 8]
                         : sOccP[(ip - pOi) * HWF + (jp - pOj)];
        bool b;
        if (!oi && !oj) { occ = tl; b = false; }
        else if (oi && !oj) {
            float bl = FIRST ? q257[((ip + 1) * 8) * 257 + jp * 8]
                             : sOccP[(ip + 1 - pOi) * HWF + (jp - pOj)];
            occ = 0.5f * (tl + bl);
            b = (tl > BAL) != (bl > BAL);
        } else if (!oi && oj) {
            float tr = FIRST ? q257[(ip * 8) * 257 + (jp + 1) * 8]
                             : sOccP[(ip - pOi) * HWF + (jp + 1 - pOj)];
            occ = 0.5f * (tl + tr);
            b = (tl > BAL) != (tr > BAL);
        } else {
            float bl = FIRST ? q257[((ip + 1) * 8) * 257 + jp * 8]
                             : sOccP[(ip + 1 - pOi) * HWF + (jp - pOj)];
            float tr = FIRST ? q257[(ip * 8) * 257 + (jp + 1) * 8]
                             : sOccP[(ip - pOi) * HWF + (jp + 1 - pOj)];
            float br = FIRST ? q257[((ip + 1) * 8) * 257 + (jp + 1) * 8]
                             : sOccP[(ip + 1 - pOi) * HWF + (jp + 1 - pOj)];
            occ = 0.5f * (0.5f * (tl + bl) + 0.5f * (tr + br));  // exact _up2 order
            bool m0 = tl > BAL, m1 = bl > BAL, m2 = tr > BAL, m3 = br > BAL;
            b = (m0 | m1 | m2 | m3) && !(m0 & m1 & m2 & m3);
        }
        rw = b ? 1 : 0;
        if (((fi | fj) & 1) == 0)
            cal = FIRST ? true : (sCalP[(ip - pOi) * HWF + (jp - pOj)] != 0);
    }
    sRaw[c] = rw; sCfA[c] = 0; sCfB[c] = 0;

    if (__syncthreads_or(rw)) {
        u8 cf = 0;
        if (li >= 1 && li < HWF - 1 && lj >= 1 && lj < HWF - 1 && inG) {
            bool b = false;
            #pragma unroll
            for (int di = -1; di <= 1; ++di)
                #pragma unroll
                for (int dj = -1; dj <= 1; ++dj)
                    if (sRaw[(li + di) * HWF + (lj + dj)]) b = true;
            b = b && !cal;
            cf = (b && (occ - BAL) * (qv - BAL) < 0.0f) ? 1 : 0;
            if (b) { occ = qv; cal = true; }
            sCfA[c] = cf;
        }
        int haveCf = __syncthreads_or((int)cf);

        #pragma unroll
        for (int it = 0; it < 3; ++it) {
            if (!haveCf) break;
            const u8* cin = (it & 1) ? sCfB : sCfA;
            u8* cout      = (it & 1) ? sCfA : sCfB;
            int lo = 2 + it, hi = HWF - 2 - it;
            u8 nc = 0;
            if (li >= lo && li < hi && lj >= lo && lj < hi && inG) {
                bool any = false;
                #pragma unroll
                for (int di = -1; di <= 1; ++di)
                    #pragma unroll
                    for (int dj = -1; dj <= 1; ++dj)
                        if (cin[(li + di) * HWF + (lj + dj)]) any = true;
                bool cand = any && !cal;
                nc = (cand && (occ - BAL) * (qv - BAL) < 0.0f) ? 1 : 0;
                if (cand) { occ = qv; cal = true; }
                cout[c] = nc;
            }
            haveCf = __syncthreads_or((int)nc);
        }
    }
    occR = occ; calR = cal;
}

// ---- levels 1-3 fused, one block per 16x16 tile of the 257 grid ----
// Also emits sgn257 (occ>0.5 per core cell) for eval_fine's cheap need-check.
__global__ __launch_bounds__(NTF) void levels123_fused(
    const float* __restrict__ q257,
    float* __restrict__ occ257, u8* __restrict__ cal257,
    u8* __restrict__ sgn257)
{
    __shared__ float sOcc[NTF];
    __shared__ u8 sCal[NTF], sRaw[NTF], sCfA[NTF], sCfB[NTF];
    const int bi = blockIdx.x / 17, bj = blockIdx.x - bi * 17;
    const int c = threadIdx.x;
    const int li = c / HWF, lj = c - li * HWF;
    float occ; bool cal;

    run_level<true>(c, li, lj, 4 * bi - 7, 4 * bj - 7, 65,
                    q257, 257, 4, q257, 0, 0,
                    sOcc, sCal, sRaw, sCfA, sCfB, occ, cal);
    sOcc[c] = occ; sCal[c] = cal ? 1 : 0;
    __syncthreads();
    run_level<false>(c, li, lj, 8 * bi - 6, 8 * bj - 6, 129,
                     q257, 257, 2, q257, 4 * bi - 7, 4 * bj - 7,
                     sOcc, sCal, sRaw, sCfA, sCfB, occ, cal);
    sOcc[c] = occ; sCal[c] = cal ? 1 : 0;
    __syncthreads();
    run_level<false>(c, li, lj, 16 * bi - 4, 16 * bj - 4, 257,
                     q257, 257, 1, q257, 8 * bi - 6, 8 * bj - 6,
                     sOcc, sCal, sRaw, sCfA, sCfB, occ, cal);

    const int fi = 16 * bi - 4 + li, fj = 16 * bj - 4 + lj;
    if (li >= 4 && li < 20 && lj >= 4 && lj < 20 && fi < 257 && fj < 257) {
        occ257[fi * 257 + fj] = occ;
        cal257[fi * 257 + fj] = cal ? 1 : 0;
        sgn257[fi * 257 + fj] = (occ > 0.5f) ? 1 : 0;
    }
}

// ---- level 4 standalone: one block per 16x16 tile of 513, global parents ----
// q4 read moved AFTER the early-exit: write-through tiles never touch q4.
__global__ __launch_bounds__(NTF) void level4_kernel(
    const float* __restrict__ occP, const u8* __restrict__ calcP,
    const float* __restrict__ q4, float* __restrict__ out)
{
    __shared__ u8 sRaw[NTF], sCfA[NTF], sCfB[NTF];
    const int bi = blockIdx.x / 33, bj = blockIdx.x - bi * 33;
    const int fi0 = bi * 16 - 4, fj0 = bj * 16 - 4;
    const int c = threadIdx.x;
    const int li = c / HWF, lj = c - li * HWF;
    const int fi = fi0 + li, fj = fj0 + lj;
    const bool inG = (fi >= 0 && fi < 513 && fj >= 0 && fj < 513);
    const float BAL = 0.5f;

    float occ = 0.5f;
    u8 rw = 0; bool cal = false;
    if (inG) {
        int ip = fi >> 1, jp = fj >> 1;
        float tl = occP[ip * 257 + jp];
        int oi = fi & 1, oj = fj & 1;
        bool b;
        if (!oi && !oj) { occ = tl; b = false; }
        else if (oi && !oj) {
            float bl = occP[(ip + 1) * 257 + jp];
            occ = 0.5f * (tl + bl);
            b = (tl > BAL) != (bl > BAL);
        } else if (!oi && oj) {
            float tr = occP[ip * 257 + jp + 1];
            occ = 0.5f * (tl + tr);
            b = (tl > BAL) != (tr > BAL);
        } else {
            float bl = occP[(ip + 1) * 257 + jp];
            float tr = occP[ip * 257 + jp + 1];
            float br = occP[(ip + 1) * 257 + jp + 1];
            occ = 0.5f * (0.5f * (tl + bl) + 0.5f * (tr + br));  // exact _up2 order
            bool m0 = tl > BAL, m1 = bl > BAL, m2 = tr > BAL, m3 = br > BAL;
            b = (m0 | m1 | m2 | m3) && !(m0 & m1 & m2 & m3);
        }
        rw = b ? 1 : 0;
        if (((fi | fj) & 1) == 0) cal = calcP[ip * 257 + jp] != 0;
    }
    sRaw[c] = rw; sCfA[c] = 0; sCfB[c] = 0;

    if (__syncthreads_or(rw)) {
        const float qv = inG ? q4[fi * 513 + fj] : 0.5f;   // only needed tiles read q4
        u8 cf = 0;
        if (li >= 1 && li < HWF - 1 && lj >= 1 && lj < HWF - 1 && inG) {
            bool b = false;
            #pragma unroll
            for (int di = -1; di <= 1; ++di)
                #pragma unroll
                for (int dj = -1; dj <= 1; ++dj)
                    if (sRaw[(li + di) * HWF + (lj + dj)]) b = true;
            b = b && !cal;
            cf = (b && (occ - BAL) * (qv - BAL) < 0.0f) ? 1 : 0;
            if (b) { occ = qv; cal = true; }
            sCfA[c] = cf;
        }
        int haveCf = __syncthreads_or((int)cf);

        #pragma unroll
        for (int it = 0; it < 3; ++it) {
            if (!haveCf) break;
            const u8* cin = (it & 1) ? sCfB : sCfA;
            u8* cout      = (it & 1) ? sCfA : sCfB;
            int lo = 2 + it, hi = HWF - 2 - it;
            u8 nc = 0;
            if (li >= lo && li < hi && lj >= lo && lj < hi && inG) {
                bool any = false;
                #pragma unroll
                for (int di = -1; di <= 1; ++di)
                    #pragma unroll
                    for (int dj = -1; dj <= 1; ++dj)
                        if (cin[(li + di) * HWF + (lj + dj)]) any = true;
                bool cand = any && !cal;
                nc = (cand && (occ - BAL) * (qv - BAL) < 0.0f) ? 1 : 0;
                if (cand) { occ = qv; cal = true; }
                cout[c] = nc;
            }
            haveCf = __syncthreads_or((int)nc);
        }
    }

    if (li >= 4 && li < 20 && lj >= 4 && lj < 20 && inG)
        out[fi * 513 + fj] = occ;
}

extern "C" void kernel_launch(void* const* d_in, const int* in_sizes, int n_in,
                              void* d_out, int out_size, void* d_ws, size_t ws_size,
                              hipStream_t stream) {
    const float* W1   = (const float*)d_in[0];
    const float* b1   = (const float*)d_in[1];
    const float* W2   = (const float*)d_in[2];
    const float* b2   = (const float*)d_in[3];
    const float* W3   = (const float*)d_in[4];
    const float* b3   = (const float*)d_in[5];
    const float* bmin = (const float*)d_in[6];
    const float* bmax = (const float*)d_in[7];

    const int N513 = 513 * 513, N257 = 257 * 257;
    float* q257   = (float*)d_ws;
    float* occ257 = q257 + N257;
    float* q4     = occ257 + N257;
    u8*    cal257 = (u8*)(q4 + N513);
    u8*    sgn257 = cal257 + N257;
    float* out    = (float*)d_out;

    // 1) dense eval at 257 (covers all q-reads of levels 1-3 bit-exactly)
    eval_grid<<<(N257 + TM - 1) / TM, 256, 0, stream>>>(
        W1, b1, W2, b2, W3, b3, bmin, bmax, q257, 257);

    // 2) levels 1-3 fused -> refined occ257 + cal257 + sgn257
    levels123_fused<<<17 * 17, NTF, 0, stream>>>(q257, occ257, cal257, sgn257);

    // 3) masked fine eval of the 513 grid (sign-mask need-check)
    eval_fine<<<33 * 33, 512, 0, stream>>>(
        W1, b1, W2, b2, W3, b3, bmin, bmax, sgn257, q4);

    // 4) level 4 -> output
    level4_kernel<<<33 * 33, NTF, 0, stream>>>(occ257, cal257, q4, out);
}

// Round 25
// 42.996 us; speedup vs baseline: 3.3295x; 1.0072x over previous
//
#include <hip/hip_runtime.h>

typedef unsigned char u8;
typedef float f32x4 __attribute__((ext_vector_type(4)));
typedef _Float16 f16x8 __attribute__((ext_vector_type(8)));

#define DIM 128
#define TM  128
// Spill rules (r17/r20/r21/r22, measured): (a) never wrap the MFMA block in a
// runtime loop; (b) never put MORE THAN ONE mlp_wave call in a kernel; (c) MFMA
// kernels at 4- or 8-wave blocks with __launch_bounds__(N,4) only.

__device__ __forceinline__ float fast_tanh(float x) {
    float e = __builtin_amdgcn_exp2f(x * 2.885390081777927f);
    return 1.0f - 2.0f * __builtin_amdgcn_rcpf(e + 1.0f);
}
__device__ __forceinline__ float fast_sigmoid(float x) {
    float e = __builtin_amdgcn_exp2f(x * -1.4426950408889634f);
    return __builtin_amdgcn_rcpf(1.0f + e);
}

template<int NT>
__device__ __forceinline__ void stage_w2(const float* __restrict__ W2,
                                         _Float16* sW2T, int tid) {
    #pragma unroll
    for (int s = 0; s < 2048 / NT; ++s) {
        int chunk = s * NT + tid;        // 0..2047
        int n = chunk & 127, ko = chunk >> 7;
        f16x8 v;
        #pragma unroll
        for (int qq = 0; qq < 8; ++qq)
            v[qq] = (_Float16)W2[(ko * 8 + qq) * DIM + n];   // coalesced over n
        int slot = ko ^ (n & 15);
        *(f16x8*)&sW2T[n * DIM + slot * 8] = v;
    }
}

// one wave: 32 points (2 A-frags) x 128 dims; b2 folded into acc init.
__device__ __forceinline__ void mlp_wave(
    const float xs[2], const float ys[2], const _Float16* sW2T,
    const float* __restrict__ W1, const float* __restrict__ b1,
    const float* __restrict__ b2, const float* __restrict__ W3,
    int lg, int l15, float rs[2][4])
{
    f32x4 acc[2][8];
    #pragma unroll
    for (int nf = 0; nf < 8; ++nf) {
        float b2v = b2[nf * 16 + l15];
        acc[0][nf] = (f32x4)(b2v);
        acc[1][nf] = (f32x4)(b2v);
    }
    #pragma unroll
    for (int kf = 0; kf < 4; ++kf) {
        const int kbase = kf * 32 + lg * 8;
        f16x8 bh[8];
        #pragma unroll
        for (int nf = 0; nf < 8; ++nf) {
            int cc = nf * 16 + l15;
            int slot = (kf * 4 + lg) ^ l15;   // matches stage_w2 swizzle
            bh[nf] = *(const f16x8*)&sW2T[cc * DIM + slot * 8];
        }
        f32x4 wxa = *(const f32x4*)&W1[kbase];
        f32x4 wxb = *(const f32x4*)&W1[kbase + 4];
        f32x4 wya = *(const f32x4*)&W1[DIM + kbase];
        f32x4 wyb = *(const f32x4*)&W1[DIM + kbase + 4];
        f32x4 b1a = *(const f32x4*)&b1[kbase];
        f32x4 b1b = *(const f32x4*)&b1[kbase + 4];
        f16x8 ah[2];
        #pragma unroll
        for (int mf = 0; mf < 2; ++mf) {
            float x = xs[mf], y = ys[mf];
            #pragma unroll
            for (int qq = 0; qq < 4; ++qq)
                ah[mf][qq] = (_Float16)fast_tanh(fmaf(x, wxa[qq], fmaf(y, wya[qq], b1a[qq])));
            #pragma unroll
            for (int qq = 0; qq < 4; ++qq)
                ah[mf][4 + qq] = (_Float16)fast_tanh(fmaf(x, wxb[qq], fmaf(y, wyb[qq], b1b[qq])));
        }
        #pragma unroll
        for (int nf = 0; nf < 8; ++nf)
            #pragma unroll
            for (int mf = 0; mf < 2; ++mf)
                acc[mf][nf] = __builtin_amdgcn_mfma_f32_16x16x32_f16(ah[mf], bh[nf], acc[mf][nf], 0, 0, 0);
    }
    #pragma unroll
    for (int mf = 0; mf < 2; ++mf)
        #pragma unroll
        for (int rg = 0; rg < 4; ++rg) rs[mf][rg] = 0.0f;
    #pragma unroll
    for (int nf = 0; nf < 8; ++nf) {
        float w3v = W3[nf * 16 + l15];
        #pragma unroll
        for (int mf = 0; mf < 2; ++mf)
            #pragma unroll
            for (int rg = 0; rg < 4; ++rg)
                rs[mf][rg] += fast_tanh(acc[mf][nf][rg]) * w3v;
    }
    #pragma unroll
    for (int mf = 0; mf < 2; ++mf)
        #pragma unroll
        for (int rg = 0; rg < 4; ++rg) {
            float v = rs[mf][rg];
            v += __shfl_xor(v, 1);
            v += __shfl_xor(v, 2);
            v += __shfl_xor(v, 4);
            v += __shfl_xor(v, 8);
            rs[mf][rg] = v;
        }
}

// ---- dense MLP eval of an RxR grid (R-1 power of two); straight-line ----
__global__ __launch_bounds__(256, 4) void eval_grid(
    const float* __restrict__ W1, const float* __restrict__ b1,
    const float* __restrict__ W2, const float* __restrict__ b2,
    const float* __restrict__ W3, const float* __restrict__ b3,
    const float* __restrict__ bmin, const float* __restrict__ bmax,
    float* __restrict__ out, int R)
{
    __shared__ __align__(16) _Float16 sW2T[DIM * DIM];   // 32 KB
    const int N = R * R;
    const int tid = threadIdx.x;
    const int m0 = blockIdx.x * TM;
    stage_w2<256>(W2, sW2T, tid);

    const int w = tid >> 6, lane = tid & 63;
    const int l15 = lane & 15, lg = lane >> 4;

    const float inv = 1.0f / (float)(R - 1);   // power-of-two -> exact
    const float bx0 = bmin[0], by0 = bmin[1];
    const float sx = bmax[0] - bx0, sy = bmax[1] - by0;
    float xs[2], ys[2];
    #pragma unroll
    for (int mf = 0; mf < 2; ++mf) {
        int pi = m0 + w * 32 + mf * 16 + l15;
        int pg = (pi < N) ? pi : N - 1;
        int gi = pg / R, gj = pg - gi * R;
        xs[mf] = bx0 + (float)gj * inv * sx;
        ys[mf] = by0 + (float)gi * inv * sy;
    }
    __syncthreads();

    float rs[2][4];
    mlp_wave(xs, ys, sW2T, W1, b1, b2, W3, lg, l15, rs);
    if (l15 == 0) {
        float b3v = b3[0];
        #pragma unroll
        for (int mf = 0; mf < 2; ++mf)
            #pragma unroll
            for (int rg = 0; rg < 4; ++rg) {
                int po = m0 + w * 32 + mf * 16 + lg * 4 + rg;
                if (po < N) out[po] = fast_sigmoid(rs[mf][rg] + b3v);
            }
    }
}

// ---- masked fine eval of the 513 grid: one 16x16 tile per block, 512 thr ----
__global__ __launch_bounds__(512, 4) void eval_fine(
    const float* __restrict__ W1, const float* __restrict__ b1,
    const float* __restrict__ W2, const float* __restrict__ b2,
    const float* __restrict__ W3, const float* __restrict__ b3,
    const float* __restrict__ bmin, const float* __restrict__ bmax,
    const u8* __restrict__ sgn257, float* __restrict__ q4)
{
    __shared__ __align__(16) _Float16 sW2T[DIM * DIM];
    const int bi = blockIdx.x / 33, bj = blockIdx.x - bi * 33;  // 33x33 tiles
    const int ti0 = bi * 16, tj0 = bj * 16;
    const int tid = threadIdx.x;

    const int iLo = (8 * bi - 2) < 0 ? 0 : (8 * bi - 2);
    const int iHi = (8 * bi + 10) > 256 ? 256 : (8 * bi + 10);
    const int jLo = (8 * bj - 2) < 0 ? 0 : (8 * bj - 2);
    const int jHi = (8 * bj + 10) > 256 ? 256 : (8 * bj + 10);
    const u8 ref = sgn257[iLo * 257 + jLo];
    bool diff = false;
    for (int s = tid; s < 169; s += 512) {
        int ii = iLo + s / 13, jj = jLo + s % 13;
        if (ii <= iHi && jj <= jHi)
            diff |= (sgn257[ii * 257 + jj] != ref);
    }
    if (!__syncthreads_or(diff ? 1 : 0)) return;

    stage_w2<512>(W2, sW2T, tid);
    __syncthreads();

    const int w = tid >> 6, lane = tid & 63;
    const int l15 = lane & 15, lg = lane >> 4;
    const float inv = 1.0f / 512.0f;
    const float bx0 = bmin[0], by0 = bmin[1];
    const float sx = bmax[0] - bx0, sy = bmax[1] - by0;

    float xs[2], ys[2];
    #pragma unroll
    for (int mf = 0; mf < 2; ++mf) {
        int p = w * 32 + mf * 16 + l15;        // 0..255 within tile
        int gi = ti0 + (p >> 4), gj = tj0 + (p & 15);
        if (gi > 512) gi = 512;
        if (gj > 512) gj = 512;
        xs[mf] = bx0 + (float)gj * inv * sx;
        ys[mf] = by0 + (float)gi * inv * sy;
    }
    float rs[2][4];
    mlp_wave(xs, ys, sW2T, W1, b1, b2, W3, lg, l15, rs);
    if (l15 == 0) {
        float b3v = b3[0];
        #pragma unroll
        for (int mf = 0; mf < 2; ++mf)
            #pragma unroll
            for (int rg = 0; rg < 4; ++rg) {
                int p = w * 32 + mf * 16 + lg * 4 + rg;
                int gi = ti0 + (p >> 4), gj = tj0 + (p & 15);
                if (gi < 513 && gj < 513)
                    q4[gi * 513 + gj] = fast_sigmoid(rs[mf][rg] + b3v);
            }
    }
}

// ---- one refinement level on a 24x24 window, one thread per cell ----
#define HWF 24
#define NTF 576
template<bool FIRST>
__device__ __forceinline__ void run_level(
    int c, int li, int lj, int oi0, int oj0, int R,
    const float* __restrict__ qbuf, int qpitch, int qs,
    const float* __restrict__ q257, int pOi, int pOj,
    const float* sOccP, const u8* sCalP,
    u8* sRaw, u8* sCfA, u8* sCfB,
    float& occR, bool& calR)
{
    const float BAL = 0.5f;
    const int fi = oi0 + li, fj = oj0 + lj;
    const bool inG = (fi >= 0 && fi < R && fj >= 0 && fj < R);
    float occ = 0.5f, qv = 0.5f;
    u8 rw = 0; bool cal = false;
    if (inG) qv = qbuf[(fi * qs) * qpitch + fj * qs];   // issued early, used late
    if (inG) {
        int ip = fi >> 1, jp = fj >> 1;
        int oi = fi & 1, oj = fj & 1;
        float tl = FIRST ? q257[(ip * 8) * 257 + jp * 8]
                         : sOccP[(ip - pOi) * HWF + (jp - pOj)];
        bool b;
        if (!oi && !oj) { occ = tl; b = false; }
        else if (oi && !oj) {
            float bl = FIRST ? q257[((ip + 1) * 8) * 257 + jp * 8]
                             : sOccP[(ip + 1 - pOi) * HWF + (jp - pOj)];
            occ = 0.5f * (tl + bl);
            b = (tl > BAL) != (bl > BAL);
        } else if (!oi && oj) {
            float tr = FIRST ? q257[(ip * 8) * 257 + (jp + 1) * 8]
                             : sOccP[(ip - pOi) * HWF + (jp + 1 - pOj)];
            occ = 0.5f * (tl + tr);
            b = (tl > BAL) != (tr > BAL);
        } else {
            float bl = FIRST ? q257[((ip + 1) * 8) * 257 + jp * 8]
                             : sOccP[(ip + 1 - pOi) * HWF + (jp - pOj)];
            float tr = FIRST ? q257[(ip * 8) * 257 + (jp + 1) * 8]
                             : sOccP[(ip - pOi) * HWF + (jp + 1 - pOj)];
            float br = FIRST ? q257[((ip + 1) * 8) * 257 + (jp + 1) * 8]
                             : sOccP[(ip + 1 - pOi) * HWF + (jp + 1 - pOj)];
            occ = 0.5f * (0.5f * (tl + bl) + 0.5f * (tr + br));  // exact _up2 order
            bool m0 = tl > BAL, m1 = bl > BAL, m2 = tr > BAL, m3 = br > BAL;
            b = (m0 | m1 | m2 | m3) && !(m0 & m1 & m2 & m3);
        }
        rw = b ? 1 : 0;
        if (((fi | fj) & 1) == 0)
            cal = FIRST ? true : (sCalP[(ip - pOi) * HWF + (jp - pOj)] != 0);
    }
    sRaw[c] = rw; sCfA[c] = 0; sCfB[c] = 0;

    if (__syncthreads_or(rw)) {
        u8 cf = 0;
        if (li >= 1 && li < HWF - 1 && lj >= 1 && lj < HWF - 1 && inG) {
            bool b = false;
            #pragma unroll
            for (int di = -1; di <= 1; ++di)
                #pragma unroll
                for (int dj = -1; dj <= 1; ++dj)
                    if (sRaw[(li + di) * HWF + (lj + dj)]) b = true;
            b = b && !cal;
            cf = (b && (occ - BAL) * (qv - BAL) < 0.0f) ? 1 : 0;
            if (b) { occ = qv; cal = true; }
            sCfA[c] = cf;
        }
        int haveCf = __syncthreads_or((int)cf);

        #pragma unroll
        for (int it = 0; it < 3; ++it) {
            if (!haveCf) break;
            const u8* cin = (it & 1) ? sCfB : sCfA;
            u8* cout      = (it & 1) ? sCfA : sCfB;
            int lo = 2 + it, hi = HWF - 2 - it;
            u8 nc = 0;
            if (li >= lo && li < hi && lj >= lo && lj < hi && inG) {
                bool any = false;
                #pragma unroll
                for (int di = -1; di <= 1; ++di)
                    #pragma unroll
                    for (int dj = -1; dj <= 1; ++dj)
                        if (cin[(li + di) * HWF + (lj + dj)]) any = true;
                bool cand = any && !cal;
                nc = (cand && (occ - BAL) * (qv - BAL) < 0.0f) ? 1 : 0;
                if (cand) { occ = qv; cal = true; }
                cout[c] = nc;
            }
            haveCf = __syncthreads_or((int)nc);
        }
    }
    occR = occ; calR = cal;
}

// ---- levels 1-3 fused, one block per 16x16 tile of the 257 grid ----
__global__ __launch_bounds__(NTF) void levels123_fused(
    const float* __restrict__ q257,
    float* __restrict__ occ257, u8* __restrict__ cal257,
    u8* __restrict__ sgn257)
{
    __shared__ float sOcc[NTF];
    __shared__ u8 sCal[NTF], sRaw[NTF], sCfA[NTF], sCfB[NTF];
    const int bi = blockIdx.x / 17, bj = blockIdx.x - bi * 17;
    const int c = threadIdx.x;
    const int li = c / HWF, lj = c - li * HWF;
    float occ; bool cal;

    run_level<true>(c, li, lj, 4 * bi - 7, 4 * bj - 7, 65,
                    q257, 257, 4, q257, 0, 0,
                    sOcc, sCal, sRaw, sCfA, sCfB, occ, cal);
    sOcc[c] = occ; sCal[c] = cal ? 1 : 0;
    __syncthreads();
    run_level<false>(c, li, lj, 8 * bi - 6, 8 * bj - 6, 129,
                     q257, 257, 2, q257, 4 * bi - 7, 4 * bj - 7,
                     sOcc, sCal, sRaw, sCfA, sCfB, occ, cal);
    sOcc[c] = occ; sCal[c] = cal ? 1 : 0;
    __syncthreads();
    run_level<false>(c, li, lj, 16 * bi - 4, 16 * bj - 4, 257,
                     q257, 257, 1, q257, 8 * bi - 6, 8 * bj - 6,
                     sOcc, sCal, sRaw, sCfA, sCfB, occ, cal);

    const int fi = 16 * bi - 4 + li, fj = 16 * bj - 4 + lj;
    if (li >= 4 && li < 20 && lj >= 4 && lj < 20 && fi < 257 && fj < 257) {
        occ257[fi * 257 + fj] = occ;
        cal257[fi * 257 + fj] = cal ? 1 : 0;
        sgn257[fi * 257 + fj] = (occ > 0.5f) ? 1 : 0;
    }
}

// ---- level 4: TS=24 tiles of 513 (484 blocks, 1024 thr, 1 thread/cell) ----
// sgn-uniformity pre-check (13+2x24/8 -> parent region [12b-2,12b+14]) lets
// write-through tiles skip the boundary bools; raw==0 guaranteed there.
#define TS4 24
#define HW4 32
__global__ __launch_bounds__(1024) void level4_kernel(
    const float* __restrict__ occP, const u8* __restrict__ calcP,
    const u8* __restrict__ sgn257,
    const float* __restrict__ q4, float* __restrict__ out)
{
    __shared__ u8 sRaw[HW4 * HW4], sCfA[HW4 * HW4], sCfB[HW4 * HW4];
    const int nT = 22;                       // ceil(513/24)
    const int bi = blockIdx.x / nT, bj = blockIdx.x - bi * nT;
    const int fi0 = bi * TS4 - 4, fj0 = bj * TS4 - 4;
    const int c = threadIdx.x;
    const int li = c / HW4, lj = c - li * HW4;
    const int fi = fi0 + li, fj = fj0 + lj;
    const bool inG = (fi >= 0 && fi < 513 && fj >= 0 && fj < 513);
    const float BAL = 0.5f;

    // sgn-uniformity over parent region [12b-3, 12b+14]^2 (covers window
    // parents [fi0/2-1, (fi0+HW4)/2+1] = [12b-3, 12b+14], 18x18 = 324 cells)
    const int iLo = (12 * bi - 3) < 0 ? 0 : (12 * bi - 3);
    const int iHi = (12 * bi + 14) > 256 ? 256 : (12 * bi + 14);
    const int jLo = (12 * bj - 3) < 0 ? 0 : (12 * bj - 3);
    const int jHi = (12 * bj + 14) > 256 ? 256 : (12 * bj + 14);
    bool diff = false;
    if (c < 324) {
        int ii = iLo + c / 18, jj = jLo + c % 18;
        if (ii <= iHi && jj <= jHi)
            diff = (sgn257[ii * 257 + jj] != sgn257[iLo * 257 + jLo]);
    }
    const bool needFull = __syncthreads_or(diff ? 1 : 0);

    // upsample (always needed for occ); raw only when needFull
    float occ = 0.5f;
    u8 rw = 0; bool cal = false;
    if (inG) {
        int ip = fi >> 1, jp = fj >> 1;
        float tl = occP[ip * 257 + jp];
        int oi = fi & 1, oj = fj & 1;
        bool b = false;
        if (!oi && !oj) { occ = tl; }
        else if (oi && !oj) {
            float bl = occP[(ip + 1) * 257 + jp];
            occ = 0.5f * (tl + bl);
            b = (tl > BAL) != (bl > BAL);
        } else if (!oi && oj) {
            float tr = occP[ip * 257 + jp + 1];
            occ = 0.5f * (tl + tr);
            b = (tl > BAL) != (tr > BAL);
        } else {
            float bl = occP[(ip + 1) * 257 + jp];
            float tr = occP[ip * 257 + jp + 1];
            float br = occP[(ip + 1) * 257 + jp + 1];
            occ = 0.5f * (0.5f * (tl + bl) + 0.5f * (tr + br));  // exact _up2 order
            bool m0 = tl > BAL, m1 = bl > BAL, m2 = tr > BAL, m3 = br > BAL;
            b = (m0 | m1 | m2 | m3) && !(m0 & m1 & m2 & m3);
        }
        rw = (needFull && b) ? 1 : 0;
        if (((fi | fj) & 1) == 0) cal = calcP[ip * 257 + jp] != 0;
    }

    if (needFull) {
        sRaw[c] = rw; sCfA[c] = 0; sCfB[c] = 0;
        if (__syncthreads_or(rw)) {
            const float qv = inG ? q4[fi * 513 + fj] : 0.5f;
            u8 cf = 0;
            if (li >= 1 && li < HW4 - 1 && lj >= 1 && lj < HW4 - 1 && inG) {
                bool b = false;
                #pragma unroll
                for (int di = -1; di <= 1; ++di)
                    #pragma unroll
                    for (int dj = -1; dj <= 1; ++dj)
                        if (sRaw[(li + di) * HW4 + (lj + dj)]) b = true;
                b = b && !cal;
                cf = (b && (occ - BAL) * (qv - BAL) < 0.0f) ? 1 : 0;
                if (b) { occ = qv; cal = true; }
                sCfA[c] = cf;
            }
            int haveCf = __syncthreads_or((int)cf);

            #pragma unroll
            for (int it = 0; it < 3; ++it) {
                if (!haveCf) break;
                const u8* cin = (it & 1) ? sCfB : sCfA;
                u8* cout      = (it & 1) ? sCfA : sCfB;
                int lo = 2 + it, hi = HW4 - 2 - it;
                u8 nc = 0;
                if (li >= lo && li < hi && lj >= lo && lj < hi && inG) {
                    bool any = false;
                    #pragma unroll
                    for (int di = -1; di <= 1; ++di)
                        #pragma unroll
                        for (int dj = -1; dj <= 1; ++dj)
                            if (cin[(li + di) * HW4 + (lj + dj)]) any = true;
                    bool cand = any && !cal;
                    nc = (cand && (occ - BAL) * (qv - BAL) < 0.0f) ? 1 : 0;
                    if (cand) { occ = qv; cal = true; }
                    cout[c] = nc;
                }
                haveCf = __syncthreads_or((int)nc);
            }
        }
    }

    if (li >= 4 && li < 4 + TS4 && lj >= 4 && lj < 4 + TS4 && inG)
        out[fi * 513 + fj] = occ;
}

extern "C" void kernel_launch(void* const* d_in, const int* in_sizes, int n_in,
                              void* d_out, int out_size, void* d_ws, size_t ws_size,
                              hipStream_t stream) {
    const float* W1   = (const float*)d_in[0];
    const float* b1   = (const float*)d_in[1];
    const float* W2   = (const float*)d_in[2];
    const float* b2   = (const float*)d_in[3];
    const float* W3   = (const float*)d_in[4];
    const float* b3   = (const float*)d_in[5];
    const float* bmin = (const float*)d_in[6];
    const float* bmax = (const float*)d_in[7];

    const int N513 = 513 * 513, N257 = 257 * 257;
    float* q257   = (float*)d_ws;
    float* occ257 = q257 + N257;
    float* q4     = occ257 + N257;
    u8*    cal257 = (u8*)(q4 + N513);
    u8*    sgn257 = cal257 + N257;
    float* out    = (float*)d_out;

    // 1) dense eval at 257 (covers all q-reads of levels 1-3 bit-exactly)
    eval_grid<<<(N257 + TM - 1) / TM, 256, 0, stream>>>(
        W1, b1, W2, b2, W3, b3, bmin, bmax, q257, 257);

    // 2) levels 1-3 fused -> refined occ257 + cal257 + sgn257
    levels123_fused<<<17 * 17, NTF, 0, stream>>>(q257, occ257, cal257, sgn257);

    // 3) masked fine eval of the 513 grid (sign-mask need-check)
    eval_fine<<<33 * 33, 512, 0, stream>>>(
        W1, b1, W2, b2, W3, b3, bmin, bmax, sgn257, q4);

    // 4) level 4 -> output (TS=24, 484 blocks, sgn pre-check)
    level4_kernel<<<22 * 22, 1024, 0, stream>>>(occ257, cal257, sgn257, q4, out);
}